// Round 13
// baseline (958.267 us; speedup 1.0000x reference)
//
#include <hip/hip_runtime.h>
#include <math.h>

// ---------- types / constants ----------
typedef __bf16 bf16x8 __attribute__((ext_vector_type(8)));
typedef short  s16x8  __attribute__((ext_vector_type(8)));
typedef float  f32x4  __attribute__((ext_vector_type(4)));

static constexpr int BSZ = 4, SEQ = 512, DM = 768;
static constexpr int DIN = 1536, NH = 48, HP = 32, NS = 64;
static constexpr int CDIM = 1664;          // DIN + 2*NS
static constexpr int PROJ_IN = 3248;
static constexpr int LDZX = 3328;          // PROJ_IN padded to x128
static constexpr int ROWS = BSZ * SEQ;     // 2048
static constexpr int EMBED = 1536;
static constexpr int NLAYERS = 12;

using gptr_t = const __attribute__((address_space(1))) void*;
using lptr_t = __attribute__((address_space(3))) void*;

__device__ __forceinline__ unsigned short f2bf(float f) {
  unsigned u = __builtin_bit_cast(unsigned, f);
  u += 0x7FFF + ((u >> 16) & 1);           // RNE
  return (unsigned short)(u >> 16);
}
__device__ __forceinline__ float bf2f(unsigned short u) {
  unsigned v = (unsigned)u << 16;
  return __builtin_bit_cast(float, v);
}
__device__ __forceinline__ float sigm(float x) { return 1.f / (1.f + __expf(-x)); }
__device__ __forceinline__ float sp(float x) { return (x > 15.f) ? x : log1pf(__expf(x)); }

__device__ __forceinline__ void gll16(const void* g, void* l) {
  __builtin_amdgcn_global_load_lds((gptr_t)g, (lptr_t)l, 16, 0, 0);
}
__device__ __forceinline__ f32x4 mfma16(s16x8 a, s16x8 b, f32x4 c) {
  return __builtin_amdgcn_mfma_f32_16x16x32_bf16(
      __builtin_bit_cast(bf16x8, a), __builtin_bit_cast(bf16x8, b), c, 0, 0, 0);
}

template <int NW>
__device__ __forceinline__ float block_sum(float v) {
#pragma unroll
  for (int o = 32; o; o >>= 1) v += __shfl_xor(v, o);
  __shared__ float red[NW];
  if ((threadIdx.x & 63) == 0) red[threadIdx.x >> 6] = v;
  __syncthreads();
  float s = red[0];
#pragma unroll
  for (int i = 1; i < NW; ++i) s += red[i];
  return s;
}

// ---------- embed: writes x fp32, x16 bf16, ssq1p (24 slots, slot 0) ----------
__global__ void embed_k(const int* __restrict__ tok, const float* __restrict__ eW,
                        float* __restrict__ x, unsigned short* __restrict__ x16,
                        float* __restrict__ ssq1p) {
  int bt = blockIdx.x, tid = threadIdx.x;   // 192 threads
  float4 v = ((const float4*)(eW + (size_t)tok[bt] * DM))[tid];
  ((float4*)(x + (size_t)bt * DM))[tid] = v;
  unsigned long long pk =
      (unsigned long long)f2bf(v.x) | ((unsigned long long)f2bf(v.y) << 16) |
      ((unsigned long long)f2bf(v.z) << 32) | ((unsigned long long)f2bf(v.w) << 48);
  *(unsigned long long*)(x16 + (size_t)bt * DM + tid * 4) = pk;
  float ss = v.x * v.x + v.y * v.y + v.z * v.z + v.w * v.w;
  float tot = block_sum<3>(ss);
  if (tid < 24) ssq1p[(size_t)bt * 24 + tid] = (tid == 0) ? tot : 0.f;
}

// ---------- fp32 (K x N) -> bf16 (Npad x K) transpose, fold per-k scale ----------
// block 256 thr, tile 64(n) x 32(k); float4 reads, 8B writes
// phase-2 mapping {n=f&63, k8=f>>6}: per-wave n spans 64 -> LDS read 2-way (free)
__global__ void transpose_cvt(const float* __restrict__ W, const float* __restrict__ sc,
                              unsigned short* __restrict__ Wt, int K, int N, int Npad) {
  __shared__ float tile[32][68];
  int l = blockIdx.z;
  const float* Wl = W + (size_t)l * K * N;
  const float* scl = sc + (size_t)l * K;
  unsigned short* Wtl = Wt + (size_t)l * Npad * K;
  int nb = blockIdx.x * 64, kb = blockIdx.y * 32;
  int tid = threadIdx.x;
#pragma unroll
  for (int rep = 0; rep < 2; ++rep) {
    int f = rep * 256 + tid;
    int k = f >> 4, c4 = f & 15;
    int n = nb + c4 * 4;
    float s = scl[kb + k];
    float4 v = {0.f, 0.f, 0.f, 0.f};
    if (n + 3 < N) {
      v = *(const float4*)(Wl + (size_t)(kb + k) * N + n);
    } else if (n < N) {
      float t_[4] = {0.f, 0.f, 0.f, 0.f};
      for (int j = 0; j < 4; ++j) if (n + j < N) t_[j] = Wl[(size_t)(kb + k) * N + n + j];
      v = {t_[0], t_[1], t_[2], t_[3]};
    }
    tile[k][c4 * 4 + 0] = v.x * s; tile[k][c4 * 4 + 1] = v.y * s;
    tile[k][c4 * 4 + 2] = v.z * s; tile[k][c4 * 4 + 3] = v.w * s;
  }
  __syncthreads();
#pragma unroll
  for (int rep = 0; rep < 2; ++rep) {
    int f = rep * 256 + tid;
    int n = f & 63, k8 = f >> 6;
    unsigned long long pk =
        (unsigned long long)f2bf(tile[k8 * 4 + 0][n]) |
        ((unsigned long long)f2bf(tile[k8 * 4 + 1][n]) << 16) |
        ((unsigned long long)f2bf(tile[k8 * 4 + 2][n]) << 32) |
        ((unsigned long long)f2bf(tile[k8 * 4 + 3][n]) << 48);
    *(unsigned long long*)(Wtl + (size_t)(nb + n) * K + kb + k8 * 4) = pk;
  }
}

// ---------- bf16 MFMA GEMM, dbuf LDS + raw barriers + counted vmcnt (round-5 structure) ----
// Epilogue scales output by rs[row] = rsqrt(mean(ssqp[row])+eps)  (fused rmsnorm).
// MODE 0: split-write -> (zb bf16 | xbc fp32 | dtraw fp32)
// MODE 1: x = x + rs*acc (fp32), also write x16 bf16 and ssq1p partials (24 slots)
template <int BM, int BN, int MODE>
__global__ __launch_bounds__(256) void gemm_k(
    const unsigned short* __restrict__ A, const unsigned short* __restrict__ Bt,
    int K, const float* __restrict__ ssqp, void* __restrict__ O0,
    void* __restrict__ O1, void* __restrict__ O2,
    unsigned short* __restrict__ x16o, float* __restrict__ ssqo) {
  constexpr int AIT = BM / 32, BIT = BN / 32, NST = AIT + BIT;
  constexpr int FM = BM / 32, FN = BN / 32;
  constexpr int NSSQ = (MODE == 0) ? 24 : 48;
  constexpr float INVD = (MODE == 0) ? (1.f / 768.f) : (1.f / 1536.f);
  __shared__ unsigned short lA[2][BM * 64], lB[2][BN * 64];
  __shared__ float rss[BM];
  int tid = threadIdx.x, lane = tid & 63, wv = tid >> 6;
  // bijective XCD swizzle (grid % 8 == 0 for both GEMMs)
  int flat = blockIdx.y * gridDim.x + blockIdx.x;
  int q8 = (gridDim.x * gridDim.y) >> 3;
  int nf = (flat & 7) * q8 + (flat >> 3);
  int bx = nf % gridDim.x, by = nf / gridDim.x;
  int m0 = by * BM, n0 = bx * BN;
  int wm = (wv >> 1) * (BM / 2), wn = (wv & 1) * (BN / 2);
  int NK = K >> 6;
  auto stage = [&](int kt, int buf) {
#pragma unroll
    for (int i = 0; i < AIT; ++i) {
      int flt = i * 256 + tid, rr = flt >> 3, cc = flt & 7;
      gll16(A + (size_t)(m0 + rr) * K + kt + (cc ^ (rr & 7)) * 8, (char*)lA[buf] + flt * 16);
    }
#pragma unroll
    for (int i = 0; i < BIT; ++i) {
      int flt = i * 256 + tid, rr = flt >> 3, cc = flt & 7;
      gll16(Bt + (size_t)(n0 + rr) * K + kt + (cc ^ (rr & 7)) * 8, (char*)lB[buf] + flt * 16);
    }
  };
  stage(0, 0);
  if (tid < BM) {
    const float* p = ssqp + (size_t)(m0 + tid) * NSSQ;
    float s = 0.f;
#pragma unroll
    for (int j = 0; j < NSSQ; ++j) s += p[j];
    rss[tid] = rsqrtf(s * INVD + 1e-5f);
  }
  __syncthreads();
  f32x4 acc[FM][FN] = {};
  for (int i = 0; i < NK; ++i) {
    if (i + 1 < NK) {
      stage((i + 1) << 6, (i + 1) & 1);
      asm volatile("s_waitcnt vmcnt(%0)" :: "i"(NST) : "memory");
    } else {
      asm volatile("s_waitcnt vmcnt(0)" ::: "memory");
    }
    __builtin_amdgcn_s_barrier();
    __builtin_amdgcn_sched_barrier(0);
    const unsigned short* cA = lA[i & 1];
    const unsigned short* cB = lB[i & 1];
#pragma unroll
    for (int ks = 0; ks < 2; ++ks) {
      s16x8 a[FM], b[FN];
#pragma unroll
      for (int mi = 0; mi < FM; ++mi) {
        int row = wm + mi * 16 + (lane & 15);
        int ch = (ks * 4 + (lane >> 4)) ^ (row & 7);
        a[mi] = *(const s16x8*)((const char*)cA + row * 128 + ch * 16);
      }
#pragma unroll
      for (int nj = 0; nj < FN; ++nj) {
        int row = wn + nj * 16 + (lane & 15);
        int ch = (ks * 4 + (lane >> 4)) ^ (row & 7);
        b[nj] = *(const s16x8*)((const char*)cB + row * 128 + ch * 16);
      }
#pragma unroll
      for (int mi = 0; mi < FM; ++mi)
#pragma unroll
        for (int nj = 0; nj < FN; ++nj)
          acc[mi][nj] = mfma16(a[mi], b[nj], acc[mi][nj]);
    }
    __builtin_amdgcn_s_barrier();
  }
#pragma unroll
  for (int mi = 0; mi < FM; ++mi) {
    int rl0 = wm + mi * 16 + ((lane >> 4) << 2);
    float rsr[4];
#pragma unroll
    for (int rg = 0; rg < 4; ++rg) rsr[rg] = rss[rl0 + rg];
    float part[4] = {0.f, 0.f, 0.f, 0.f};
#pragma unroll
    for (int nj = 0; nj < FN; ++nj) {
      int col = n0 + wn + nj * 16 + (lane & 15);
#pragma unroll
      for (int rg = 0; rg < 4; ++rg) {
        int row = m0 + rl0 + rg;
        float vv = acc[mi][nj][rg] * rsr[rg];
        if constexpr (MODE == 0) {
          if (n0 < DIN) {
            ((unsigned short*)O0)[(size_t)row * DIN + col] = f2bf(vv);
          } else if (n0 < DIN + CDIM) {
            ((float*)O1)[(size_t)row * CDIM + (col - DIN)] = vv;
          } else {
            int c2 = col - (DIN + CDIM);
            if (c2 < NH) ((float*)O2)[(size_t)row * NH + c2] = vv;
          }
        } else {
          size_t idx = (size_t)row * DM + col;
          float xn = vv + ((float*)O0)[idx];
          ((float*)O0)[idx] = xn;
          x16o[idx] = f2bf(xn);
          part[rg] += xn * xn;
        }
      }
    }
    if constexpr (MODE == 1) {
#pragma unroll
      for (int rg = 0; rg < 4; ++rg) {
#pragma unroll
        for (int off = 1; off < 16; off <<= 1) part[rg] += __shfl_xor(part[rg], off);
      }
      if ((lane & 15) == 0) {
#pragma unroll
        for (int rg = 0; rg < 4; ++rg)
          ssqo[(size_t)(m0 + rl0 + rg) * 24 + bx * 2 + (wn >> 5)] = part[rg];
      }
    }
  }
}

// ---------- conv(K=4)+silu; emits bf16 xs, dtx^T, B, C + fp32 dts (softplus'd) ----------
__global__ __launch_bounds__(256) void conv_dt_k(
    const float* __restrict__ xbc, const float* __restrict__ cw, const float* __restrict__ cb,
    const float* __restrict__ dtraw, const float* __restrict__ dbias,
    unsigned short* __restrict__ xs16, unsigned short* __restrict__ dtxT,
    unsigned short* __restrict__ Bbf, unsigned short* __restrict__ Cbf,
    float* __restrict__ dts) {
  __shared__ float stg[11][256];
  __shared__ float dtl[8][48];
  int tid = threadIdx.x;
  int chunk = blockIdx.x;                  // 0..6
  int bt0 = blockIdx.y * 8;
  int t0 = bt0 & (SEQ - 1);
  int cbase = chunk * 256;
  // vectorized float4 staging: 11 rows x 64 float4
  for (int f = tid; f < 11 * 64; f += 256) {
    int row = f >> 6, c4 = f & 63;
    int s = t0 - 3 + row;
    int col = cbase + c4 * 4;
    float4 v = {0.f, 0.f, 0.f, 0.f};
    if (s >= 0 && col + 3 < CDIM) {
      v = *(const float4*)(xbc + (size_t)(bt0 - 3 + row) * CDIM + col);
    }
    *(float4*)&stg[row][c4 * 4] = v;
  }
  if (chunk < 6) {
    for (int idx = tid; idx < 384; idx += 256) {
      int r = idx / 48, hh = idx - r * 48;
      dtl[r][hh] = sp(dtraw[(size_t)(bt0 + r) * NH + hh] + dbias[hh]);
    }
  }
  __syncthreads();
  int c = cbase + tid;
  if (chunk < 6) {
    float w0 = cw[c * 4], w1 = cw[c * 4 + 1], w2 = cw[c * 4 + 2], w3 = cw[c * 4 + 3];
    float bias = cb[c];
    int hh = c >> 5, p = c & 31, b = bt0 >> 9;
    s16x8 pk;
#pragma unroll
    for (int r = 0; r < 8; ++r) {
      float a = bias + stg[r][tid] * w0 + stg[r + 1][tid] * w1 + stg[r + 2][tid] * w2 +
                stg[r + 3][tid] * w3;
      float sv = a * sigm(a);
      xs16[(size_t)(bt0 + r) * DIN + c] = f2bf(sv);
      pk[r] = (short)f2bf(sv * dtl[r][hh]);
    }
    *reinterpret_cast<s16x8*>(dtxT + ((((size_t)b * NH + hh) * HP + p) * SEQ + t0)) = pk;
  } else if (tid < 128) {
    int cc = DIN + tid;
    float w0 = cw[cc * 4], w1 = cw[cc * 4 + 1], w2 = cw[cc * 4 + 2], w3 = cw[cc * 4 + 3];
    float bias = cb[cc];
#pragma unroll
    for (int r = 0; r < 8; ++r) {
      float a = bias + stg[r][tid] * w0 + stg[r + 1][tid] * w1 + stg[r + 2][tid] * w2 +
                stg[r + 3][tid] * w3;
      float sv = a * sigm(a);
      if (tid < 64) Bbf[(size_t)(bt0 + r) * NS + tid] = f2bf(sv);
      else          Cbf[(size_t)(bt0 + r) * NS + (tid - 64)] = f2bf(sv);
    }
  } else if (tid < 176) {
    int hh = tid - 128;
    float bias_ = dbias[hh];
    float v[8];
#pragma unroll
    for (int r = 0; r < 8; ++r) v[r] = sp(dtraw[(size_t)(bt0 + r) * NH + hh] + bias_);
    float4 a4 = {v[0], v[1], v[2], v[3]}, b4 = {v[4], v[5], v[6], v[7]};
    float* dp = dts + ((size_t)(bt0 >> 9) * NH + hh) * SEQ + t0;
    *(float4*)dp = a4;
    *(float4*)(dp + 4) = b4;
  }
}

// ---------- SSM: decay-truncated tiled semiseparable matmul + fused silu(z) gate ----------
__global__ __launch_bounds__(256) void scan_k(
    const unsigned short* __restrict__ Bbf, const unsigned short* __restrict__ Cbf,
    const unsigned short* __restrict__ dtxT, const unsigned short* __restrict__ xs16,
    const float* __restrict__ dts, const unsigned short* __restrict__ zb,
    const float* __restrict__ alog, const float* __restrict__ Dvec,
    unsigned short* __restrict__ g16, float* __restrict__ ssq2p) {
  __shared__ unsigned short CbPt[64 * 64];   // C tile, then reused as P tile
  __shared__ unsigned short Bb[2][64 * 64], Dx[2][32 * 64];
  __shared__ float lsb[SEQ];
  __shared__ float wtot[4];
  __shared__ int sfirst;
  int tid = threadIdx.x, lane = tid & 63, wv = tid >> 6;
  int tb = blockIdx.x, h = blockIdx.y, b = blockIdx.z;
  int t0 = tb * 64;
  const unsigned short* dxrow = dtxT + ((size_t)b * NH + h) * HP * SEQ;

  // issue C staging early
#pragma unroll
  for (int i = 0; i < 2; ++i) {
    int flt = i * 256 + tid, rr = flt >> 3, cc = flt & 7;
    gll16(Cbf + (size_t)(b * SEQ + t0 + rr) * NS + (cc ^ (rr & 7)) * 8, (char*)CbPt + flt * 16);
  }
  // ls = cumsum(dt*A) via shfl-scan (dt already softplus'd: dts)
  float Ah = -__expf(alog[h]);
  int t2 = tid * 2;
  float2 dv = *(const float2*)(dts + ((size_t)b * NH + h) * SEQ + t2);
  float d0 = dv.x * Ah, d1 = dv.y * Ah;
  float ps = d0 + d1;
  float v = ps;
#pragma unroll
  for (int off = 1; off < 64; off <<= 1) {
    float u = __shfl_up(v, off);
    if (lane >= off) v += u;
  }
  if (lane == 63) wtot[wv] = v;
  if (tid == 0) sfirst = tb;
  __syncthreads();
  float wpre = 0.f;
#pragma unroll
  for (int w = 0; w < 3; ++w) wpre += (w < wv) ? wtot[w] : 0.f;
  float excl = v + wpre - ps;
  lsb[t2] = excl + d0;
  lsb[t2 + 1] = excl + d0 + d1;
  __syncthreads();
  float REF = lsb[t0];
  // earliest s-tile with non-negligible decay (monotone predicate)
  if (tid < tb && (REF - lsb[tid * 64 + 63] >= -9.f)) atomicMin(&sfirst, tid);
  __syncthreads();
  int st0 = sfirst;

  // stage B/Dx for st0
#pragma unroll
  for (int i = 0; i < 2; ++i) {
    int flt = i * 256 + tid, rr = flt >> 3, cc = flt & 7;
    gll16(Bbf + (size_t)(b * SEQ + st0 * 64 + rr) * NS + (cc ^ (rr & 7)) * 8,
          (char*)Bb[st0 & 1] + flt * 16);
  }
  { int rr = tid >> 3, cc = tid & 7;
    gll16(dxrow + (size_t)rr * SEQ + st0 * 64 + (cc ^ (rr & 7)) * 8,
          (char*)Dx[st0 & 1] + tid * 16); }

  float lt[4], elt[4];
  int trb = wv * 16 + ((lane >> 4) << 2);
#pragma unroll
  for (int rg = 0; rg < 4; ++rg) {
    lt[rg] = lsb[t0 + trb + rg];
    elt[rg] = __expf(lt[rg] - REF);
  }
  s16x8 aC[2];
  f32x4 yacc[2] = {};

  for (int st = st0; st <= tb; ++st) {
    int s0 = st * 64;
    if (st < tb) {
      int s1 = s0 + 64;
#pragma unroll
      for (int i = 0; i < 2; ++i) {
        int flt = i * 256 + tid, rr = flt >> 3, cc = flt & 7;
        gll16(Bbf + (size_t)(b * SEQ + s1 + rr) * NS + (cc ^ (rr & 7)) * 8,
              (char*)Bb[(st + 1) & 1] + flt * 16);
      }
      { int rr = tid >> 3, cc = tid & 7;
        gll16(dxrow + (size_t)rr * SEQ + s1 + (cc ^ (rr & 7)) * 8,
              (char*)Dx[(st + 1) & 1] + tid * 16); }
      asm volatile("s_waitcnt vmcnt(3)" ::: "memory");
    } else {
      asm volatile("s_waitcnt vmcnt(0)" ::: "memory");
    }
    __builtin_amdgcn_s_barrier();
    __builtin_amdgcn_sched_barrier(0);
    const unsigned short* Bcur = Bb[st & 1];
    const unsigned short* Dcur = Dx[st & 1];
    if (st == st0) {   // C fragments (CbPt later reused as Pt; wave-local rows, safe)
#pragma unroll
      for (int ks = 0; ks < 2; ++ks) {
        int row = wv * 16 + (lane & 15);
        int ch = (ks * 4 + (lane >> 4)) ^ (row & 7);
        aC[ks] = *(const s16x8*)((const char*)CbPt + row * 128 + ch * 16);
      }
    }
    float lsv[4];
#pragma unroll
    for (int sq = 0; sq < 4; ++sq) lsv[sq] = lsb[s0 + sq * 16 + (lane & 15)];
    // G = C . B^T (wave's 16-row t-strip)
    f32x4 gf[4] = {};
    __builtin_amdgcn_s_setprio(1);
#pragma unroll
    for (int sq = 0; sq < 4; ++sq)
#pragma unroll
      for (int ks = 0; ks < 2; ++ks) {
        int row = sq * 16 + (lane & 15);
        int ch = (ks * 4 + (lane >> 4)) ^ (row & 7);
        s16x8 bB = *(const s16x8*)((const char*)Bcur + row * 128 + ch * 16);
        gf[sq] = mfma16(aC[ks], bB, gf[sq]);
      }
    __builtin_amdgcn_s_setprio(0);
    // decay weighting + write P (into CbPt)
    if (st < tb) {
      float es[4];
#pragma unroll
      for (int sq = 0; sq < 4; ++sq) es[sq] = __expf(REF - lsv[sq]);
#pragma unroll
      for (int sq = 0; sq < 4; ++sq) {
        int scol = sq * 16 + (lane & 15);
#pragma unroll
        for (int rg = 0; rg < 4; ++rg) {
          int trow = trb + rg;
          int off = (trow * 128 + scol * 2) ^ ((trow & 7) << 4);
          *(unsigned short*)((char*)CbPt + off) = f2bf(gf[sq][rg] * (elt[rg] * es[sq]));
        }
      }
    } else {
#pragma unroll
      for (int sq = 0; sq < 4; ++sq) {
        int scol = sq * 16 + (lane & 15);
        int sg = s0 + scol;
#pragma unroll
        for (int rg = 0; rg < 4; ++rg) {
          int trow = trb + rg, tg = t0 + trow;
          float wgt = (sg <= tg) ? __expf(lt[rg] - lsv[sq]) : 0.f;
          int off = (trow * 128 + scol * 2) ^ ((trow & 7) << 4);
          *(unsigned short*)((char*)CbPt + off) = f2bf(gf[sq][rg] * wgt);
        }
      }
    }
    // Y += P @ DxT (wave-local Pt rows)
    __builtin_amdgcn_s_setprio(1);
#pragma unroll
    for (int ks = 0; ks < 2; ++ks) {
      int row = wv * 16 + (lane & 15);
      int ch = (ks * 4 + (lane >> 4)) ^ (row & 7);
      s16x8 aP = *(const s16x8*)((const char*)CbPt + row * 128 + ch * 16);
#pragma unroll
      for (int pq = 0; pq < 2; ++pq) {
        int prow = pq * 16 + (lane & 15);
        int pch = (ks * 4 + (lane >> 4)) ^ (prow & 7);
        s16x8 bD = *(const s16x8*)((const char*)Dcur + prow * 128 + pch * 16);
        yacc[pq] = mfma16(aP, bD, yacc[pq]);
      }
    }
    __builtin_amdgcn_s_setprio(0);
    __builtin_amdgcn_s_barrier();
  }
  // epilogue: y = yacc + D*xs; g = y*silu(z); write g16 + ssq2p partial
  float Dh = Dvec[h];
  float part[4] = {0.f, 0.f, 0.f, 0.f};
#pragma unroll
  for (int pq = 0; pq < 2; ++pq) {
#pragma unroll
    for (int rg = 0; rg < 4; ++rg) {
      int trow = trb + rg;
      int tg = t0 + trow;
      int p = pq * 16 + (lane & 15);
      size_t gi = (size_t)(b * SEQ + tg) * DIN + h * HP + p;
      float xv = bf2f(xs16[gi]);
      float yv = yacc[pq][rg] + Dh * xv;
      float zf = bf2f(zb[gi]);
      float g = yv * zf * sigm(zf);
      g16[gi] = f2bf(g);
      part[rg] += g * g;
    }
  }
#pragma unroll
  for (int rg = 0; rg < 4; ++rg) {
#pragma unroll
    for (int off = 1; off < 16; off <<= 1) part[rg] += __shfl_xor(part[rg], off);
  }
  if ((lane & 15) == 0) {
#pragma unroll
    for (int rg = 0; rg < 4; ++rg)
      ssq2p[(size_t)(b * SEQ + t0 + trb + rg) * 48 + h] = part[rg];
  }
}

// ---------- tail: pool partials (fused final rmsnorm), proj (+chunk reduce), l2 ----------
__global__ void pool_part_k(const float* __restrict__ x, const float* __restrict__ ssq1p,
                            float* __restrict__ pp) {
  __shared__ float rsl[64];
  int b = blockIdx.y, tc = blockIdx.z, d0 = blockIdx.x * 256, tid = threadIdx.x;
  int t0 = tc * 64;
  if (tid < 64) {
    const float* p = ssq1p + (size_t)(b * SEQ + t0 + tid) * 24;
    float s = 0.f;
#pragma unroll
    for (int j = 0; j < 24; ++j) s += p[j];
    rsl[tid] = rsqrtf(s * (1.f / DM) + 1e-5f);
  }
  __syncthreads();
  int d = d0 + tid;
  float s = 0.f;
#pragma unroll 4
  for (int i = 0; i < 64; ++i) s += x[(size_t)(b * SEQ + t0 + i) * DM + d] * rsl[i];
  pp[((size_t)b * 8 + tc) * DM + d] = s;
}
__global__ void proj_k(const float* __restrict__ pp, const float* __restrict__ fnW,
                       const float* __restrict__ pW, const float* __restrict__ pb,
                       float* __restrict__ ptmp) {
  __shared__ float pl[DM];
  __shared__ float red[4][64];
  int e0 = blockIdx.x * 64, b = blockIdx.y, tid = threadIdx.x;
  for (int i = tid; i < DM; i += 256) {
    float s = 0.f;
#pragma unroll
    for (int c = 0; c < 8; ++c) s += pp[((size_t)b * 8 + c) * DM + i];
    pl[i] = s * (1.f / SEQ) * fnW[i];
  }
  __syncthreads();
  int el = tid & 63, g = tid >> 6;
  int e = e0 + el;
  float s = 0.f;
  for (int d = g * 192; d < (g + 1) * 192; ++d)
    s += pl[d] * pW[(size_t)d * EMBED + e];
  red[g][el] = s;
  __syncthreads();
  if (g == 0) ptmp[b * EMBED + e] = red[0][el] + red[1][el] + red[2][el] + red[3][el] + pb[e];
}
__global__ void l2_k(const float* __restrict__ ptmp, float* __restrict__ out) {
  int b = blockIdx.x;
  float v[6], ss = 0.f;
#pragma unroll
  for (int i = 0; i < 6; ++i) {
    v[i] = ptmp[(size_t)b * EMBED + threadIdx.x + i * 256];
    ss += v[i] * v[i];
  }
  float tot = block_sum<4>(ss);
  float inv = 1.f / fmaxf(sqrtf(tot), 1e-12f);
#pragma unroll
  for (int i = 0; i < 6; ++i)
    out[(size_t)b * EMBED + threadIdx.x + i * 256] = v[i] * inv;
}

// ---------- launch ----------
extern "C" void kernel_launch(void* const* d_in, const int* in_sizes, int n_in,
                              void* d_out, int out_size, void* d_ws, size_t ws_size,
                              hipStream_t stream) {
  const int*   tok  = (const int*)d_in[0];
  const float* embW = (const float*)d_in[1];
  const float* lnW  = (const float*)d_in[2];
  const float* ipW  = (const float*)d_in[3];
  const float* cW   = (const float*)d_in[4];
  const float* cB   = (const float*)d_in[5];
  const float* dtB  = (const float*)d_in[6];
  const float* Alog = (const float*)d_in[7];
  const float* Dv   = (const float*)d_in[8];
  const float* nW   = (const float*)d_in[9];
  const float* opW  = (const float*)d_in[10];
  const float* fnW  = (const float*)d_in[11];
  const float* pW   = (const float*)d_in[12];
  const float* pb   = (const float*)d_in[13];
  float* out = (float*)d_out;

  char* wsp = (char*)d_ws;
  auto alloc = [&](size_t bytes) {
    char* p = wsp;
    wsp += (bytes + 255) & ~(size_t)255;
    return p;
  };
  float* x      = (float*)alloc((size_t)ROWS * DM * 4);
  float* xbc    = (float*)alloc((size_t)ROWS * CDIM * 4);
  float* dtraw  = (float*)alloc((size_t)ROWS * NH * 4);
  float* dts    = (float*)alloc((size_t)BSZ * NH * SEQ * 4);
  float* ssq1p  = (float*)alloc((size_t)ROWS * 24 * 4);
  float* ssq2p  = (float*)alloc((size_t)ROWS * 48 * 4);
  float* pp     = (float*)alloc((size_t)BSZ * 8 * DM * 4);
  float* ptmp   = (float*)alloc((size_t)BSZ * EMBED * 4);
  unsigned short* x16   = (unsigned short*)alloc((size_t)ROWS * DM * 2);
  unsigned short* zb    = (unsigned short*)alloc((size_t)ROWS * DIN * 2);
  unsigned short* xs16  = (unsigned short*)alloc((size_t)ROWS * DIN * 2);
  unsigned short* g16   = (unsigned short*)alloc((size_t)ROWS * DIN * 2);
  unsigned short* dtxT  = (unsigned short*)alloc((size_t)BSZ * NH * HP * SEQ * 2);
  unsigned short* Bbf   = (unsigned short*)alloc((size_t)ROWS * NS * 2);
  unsigned short* Cbf   = (unsigned short*)alloc((size_t)ROWS * NS * 2);
  unsigned short* wtA   = (unsigned short*)alloc((size_t)NLAYERS * LDZX * DM * 2);
  unsigned short* wtO   = (unsigned short*)alloc((size_t)NLAYERS * DM * DIN * 2);

  embed_k<<<ROWS, 192, 0, stream>>>(tok, embW, x, x16, ssq1p);
  transpose_cvt<<<dim3(LDZX / 64, DM / 32, NLAYERS), 256, 0, stream>>>(
      ipW, lnW, wtA, DM, PROJ_IN, LDZX);
  transpose_cvt<<<dim3(DM / 64, DIN / 32, NLAYERS), 256, 0, stream>>>(
      opW, nW, wtO, DIN, DM, DM);

  for (int l = 0; l < NLAYERS; ++l) {
    gemm_k<128, 64, 0><<<dim3(LDZX / 64, ROWS / 128), 256, 0, stream>>>(
        x16, wtA + (size_t)l * LDZX * DM, DM, ssq1p, zb, xbc, dtraw, nullptr, nullptr);
    conv_dt_k<<<dim3(7, ROWS / 8), 256, 0, stream>>>(
        xbc, cW + (size_t)l * CDIM * 4, cB + (size_t)l * CDIM, dtraw, dtB + l * NH,
        xs16, dtxT, Bbf, Cbf, dts);
    scan_k<<<dim3(SEQ / 64, NH, BSZ), 256, 0, stream>>>(
        Bbf, Cbf, dtxT, xs16, dts, zb, Alog + l * NH, Dv + l * NH, g16, ssq2p);
    gemm_k<64, 64, 1><<<dim3(DM / 64, ROWS / 64), 256, 0, stream>>>(
        g16, wtO + (size_t)l * DM * DIN, DIN, ssq2p, x, nullptr, nullptr, x16, ssq1p);
  }

  pool_part_k<<<dim3(DM / 256, BSZ, 8), 256, 0, stream>>>(x, ssq1p, pp);
  proj_k<<<dim3(EMBED / 64, BSZ), 256, 0, stream>>>(pp, fnW, pW, pb, ptmp);
  l2_k<<<BSZ, 256, 0, stream>>>(ptmp, out);
}

// Round 14
// 915.744 us; speedup vs baseline: 1.0464x; 1.0464x over previous
//
#include <hip/hip_runtime.h>
#include <math.h>

// ---------- types / constants ----------
typedef __bf16 bf16x8 __attribute__((ext_vector_type(8)));
typedef short  s16x8  __attribute__((ext_vector_type(8)));
typedef float  f32x4  __attribute__((ext_vector_type(4)));

static constexpr int BSZ = 4, SEQ = 512, DM = 768;
static constexpr int DIN = 1536, NH = 48, HP = 32, NS = 64;
static constexpr int CDIM = 1664;          // DIN + 2*NS
static constexpr int PROJ_IN = 3248;
static constexpr int LDZX = 3328;          // PROJ_IN padded to x128
static constexpr int ROWS = BSZ * SEQ;     // 2048
static constexpr int EMBED = 1536;
static constexpr int NLAYERS = 12;

using gptr_t = const __attribute__((address_space(1))) void*;
using lptr_t = __attribute__((address_space(3))) void*;

__device__ __forceinline__ unsigned short f2bf(float f) {
  unsigned u = __builtin_bit_cast(unsigned, f);
  u += 0x7FFF + ((u >> 16) & 1);           // RNE
  return (unsigned short)(u >> 16);
}
__device__ __forceinline__ float bf2f(unsigned short u) {
  unsigned v = (unsigned)u << 16;
  return __builtin_bit_cast(float, v);
}
__device__ __forceinline__ float sigm(float x) { return 1.f / (1.f + __expf(-x)); }
__device__ __forceinline__ float sp(float x) { return (x > 15.f) ? x : log1pf(__expf(x)); }

__device__ __forceinline__ void gll16(const void* g, void* l) {
  __builtin_amdgcn_global_load_lds((gptr_t)g, (lptr_t)l, 16, 0, 0);
}
__device__ __forceinline__ f32x4 mfma16(s16x8 a, s16x8 b, f32x4 c) {
  return __builtin_amdgcn_mfma_f32_16x16x32_bf16(
      __builtin_bit_cast(bf16x8, a), __builtin_bit_cast(bf16x8, b), c, 0, 0, 0);
}

template <int NW>
__device__ __forceinline__ float block_sum(float v) {
#pragma unroll
  for (int o = 32; o; o >>= 1) v += __shfl_xor(v, o);
  __shared__ float red[NW];
  if ((threadIdx.x & 63) == 0) red[threadIdx.x >> 6] = v;
  __syncthreads();
  float s = red[0];
#pragma unroll
  for (int i = 1; i < NW; ++i) s += red[i];
  return s;
}

// ---------- embed: writes x fp32, x16 bf16, ssq1p (24 slots, slot 0) ----------
__global__ void embed_k(const int* __restrict__ tok, const float* __restrict__ eW,
                        float* __restrict__ x, unsigned short* __restrict__ x16,
                        float* __restrict__ ssq1p) {
  int bt = blockIdx.x, tid = threadIdx.x;   // 192 threads
  float4 v = ((const float4*)(eW + (size_t)tok[bt] * DM))[tid];
  ((float4*)(x + (size_t)bt * DM))[tid] = v;
  unsigned long long pk =
      (unsigned long long)f2bf(v.x) | ((unsigned long long)f2bf(v.y) << 16) |
      ((unsigned long long)f2bf(v.z) << 32) | ((unsigned long long)f2bf(v.w) << 48);
  *(unsigned long long*)(x16 + (size_t)bt * DM + tid * 4) = pk;
  float ss = v.x * v.x + v.y * v.y + v.z * v.z + v.w * v.w;
  float tot = block_sum<3>(ss);
  if (tid < 24) ssq1p[(size_t)bt * 24 + tid] = (tid == 0) ? tot : 0.f;
}

// ---------- fp32 (K x N) -> bf16 (Npad x K) transpose, fold per-k scale ----------
// block 256 thr, tile 64(n) x 32(k); float4 reads, 8B coalesced writes
// pad 65: 65*row = row (mod 32) -> phase-2 read bank (4k8+j+n) ~2-way (free),
// phase-1 write base (k+4c4) 2-way (free). Writes stay line-coalesced (8 lanes/64B).
__global__ void transpose_cvt(const float* __restrict__ W, const float* __restrict__ sc,
                              unsigned short* __restrict__ Wt, int K, int N, int Npad) {
  __shared__ float tile[32][65];
  int l = blockIdx.z;
  const float* Wl = W + (size_t)l * K * N;
  const float* scl = sc + (size_t)l * K;
  unsigned short* Wtl = Wt + (size_t)l * Npad * K;
  int nb = blockIdx.x * 64, kb = blockIdx.y * 32;
  int tid = threadIdx.x;
#pragma unroll
  for (int rep = 0; rep < 2; ++rep) {
    int f = rep * 256 + tid;
    int k = f >> 4, c4 = f & 15;
    int n = nb + c4 * 4;
    float s = scl[kb + k];
    float4 v = {0.f, 0.f, 0.f, 0.f};
    if (n + 3 < N) {
      v = *(const float4*)(Wl + (size_t)(kb + k) * N + n);
    } else if (n < N) {
      float t_[4] = {0.f, 0.f, 0.f, 0.f};
      for (int j = 0; j < 4; ++j) if (n + j < N) t_[j] = Wl[(size_t)(kb + k) * N + n + j];
      v = {t_[0], t_[1], t_[2], t_[3]};
    }
    tile[k][c4 * 4 + 0] = v.x * s; tile[k][c4 * 4 + 1] = v.y * s;
    tile[k][c4 * 4 + 2] = v.z * s; tile[k][c4 * 4 + 3] = v.w * s;
  }
  __syncthreads();
#pragma unroll
  for (int rep = 0; rep < 2; ++rep) {
    int f = rep * 256 + tid;
    int n = f >> 3, k8 = f & 7;
    unsigned long long pk =
        (unsigned long long)f2bf(tile[k8 * 4 + 0][n]) |
        ((unsigned long long)f2bf(tile[k8 * 4 + 1][n]) << 16) |
        ((unsigned long long)f2bf(tile[k8 * 4 + 2][n]) << 32) |
        ((unsigned long long)f2bf(tile[k8 * 4 + 3][n]) << 48);
    *(unsigned long long*)(Wtl + (size_t)(nb + n) * K + kb + k8 * 4) = pk;
  }
}

// ---------- bf16 MFMA GEMM, dbuf LDS + raw barriers + counted vmcnt (round-5 structure) ----
// Epilogue scales output by rs[row] = rsqrt(mean(ssqp[row])+eps)  (fused rmsnorm).
// MODE 0: split-write -> (zb bf16 | xbc fp32 | dtraw fp32)
// MODE 1: x = x + rs*acc (fp32), also write x16 bf16 and ssq1p partials (24 slots)
template <int BM, int BN, int MODE>
__global__ __launch_bounds__(256) void gemm_k(
    const unsigned short* __restrict__ A, const unsigned short* __restrict__ Bt,
    int K, const float* __restrict__ ssqp, void* __restrict__ O0,
    void* __restrict__ O1, void* __restrict__ O2,
    unsigned short* __restrict__ x16o, float* __restrict__ ssqo) {
  constexpr int AIT = BM / 32, BIT = BN / 32, NST = AIT + BIT;
  constexpr int FM = BM / 32, FN = BN / 32;
  constexpr int NSSQ = (MODE == 0) ? 24 : 48;
  constexpr float INVD = (MODE == 0) ? (1.f / 768.f) : (1.f / 1536.f);
  __shared__ unsigned short lA[2][BM * 64], lB[2][BN * 64];
  __shared__ float rss[BM];
  int tid = threadIdx.x, lane = tid & 63, wv = tid >> 6;
  // bijective XCD swizzle (grid % 8 == 0 for both GEMMs)
  int flat = blockIdx.y * gridDim.x + blockIdx.x;
  int q8 = (gridDim.x * gridDim.y) >> 3;
  int nf = (flat & 7) * q8 + (flat >> 3);
  int bx = nf % gridDim.x, by = nf / gridDim.x;
  int m0 = by * BM, n0 = bx * BN;
  int wm = (wv >> 1) * (BM / 2), wn = (wv & 1) * (BN / 2);
  int NK = K >> 6;
  auto stage = [&](int kt, int buf) {
#pragma unroll
    for (int i = 0; i < AIT; ++i) {
      int flt = i * 256 + tid, rr = flt >> 3, cc = flt & 7;
      gll16(A + (size_t)(m0 + rr) * K + kt + (cc ^ (rr & 7)) * 8, (char*)lA[buf] + flt * 16);
    }
#pragma unroll
    for (int i = 0; i < BIT; ++i) {
      int flt = i * 256 + tid, rr = flt >> 3, cc = flt & 7;
      gll16(Bt + (size_t)(n0 + rr) * K + kt + (cc ^ (rr & 7)) * 8, (char*)lB[buf] + flt * 16);
    }
  };
  stage(0, 0);
  if (tid < BM) {
    const float* p = ssqp + (size_t)(m0 + tid) * NSSQ;
    float s = 0.f;
#pragma unroll
    for (int j = 0; j < NSSQ; ++j) s += p[j];
    rss[tid] = rsqrtf(s * INVD + 1e-5f);
  }
  __syncthreads();
  f32x4 acc[FM][FN] = {};
  for (int i = 0; i < NK; ++i) {
    if (i + 1 < NK) {
      stage((i + 1) << 6, (i + 1) & 1);
      asm volatile("s_waitcnt vmcnt(%0)" :: "i"(NST) : "memory");
    } else {
      asm volatile("s_waitcnt vmcnt(0)" ::: "memory");
    }
    __builtin_amdgcn_s_barrier();
    __builtin_amdgcn_sched_barrier(0);
    const unsigned short* cA = lA[i & 1];
    const unsigned short* cB = lB[i & 1];
#pragma unroll
    for (int ks = 0; ks < 2; ++ks) {
      s16x8 a[FM], b[FN];
#pragma unroll
      for (int mi = 0; mi < FM; ++mi) {
        int row = wm + mi * 16 + (lane & 15);
        int ch = (ks * 4 + (lane >> 4)) ^ (row & 7);
        a[mi] = *(const s16x8*)((const char*)cA + row * 128 + ch * 16);
      }
#pragma unroll
      for (int nj = 0; nj < FN; ++nj) {
        int row = wn + nj * 16 + (lane & 15);
        int ch = (ks * 4 + (lane >> 4)) ^ (row & 7);
        b[nj] = *(const s16x8*)((const char*)cB + row * 128 + ch * 16);
      }
#pragma unroll
      for (int mi = 0; mi < FM; ++mi)
#pragma unroll
        for (int nj = 0; nj < FN; ++nj)
          acc[mi][nj] = mfma16(a[mi], b[nj], acc[mi][nj]);
    }
    __builtin_amdgcn_s_barrier();
  }
#pragma unroll
  for (int mi = 0; mi < FM; ++mi) {
    int rl0 = wm + mi * 16 + ((lane >> 4) << 2);
    float rsr[4];
#pragma unroll
    for (int rg = 0; rg < 4; ++rg) rsr[rg] = rss[rl0 + rg];
    float part[4] = {0.f, 0.f, 0.f, 0.f};
#pragma unroll
    for (int nj = 0; nj < FN; ++nj) {
      int col = n0 + wn + nj * 16 + (lane & 15);
#pragma unroll
      for (int rg = 0; rg < 4; ++rg) {
        int row = m0 + rl0 + rg;
        float vv = acc[mi][nj][rg] * rsr[rg];
        if constexpr (MODE == 0) {
          if (n0 < DIN) {
            ((unsigned short*)O0)[(size_t)row * DIN + col] = f2bf(vv);
          } else if (n0 < DIN + CDIM) {
            ((float*)O1)[(size_t)row * CDIM + (col - DIN)] = vv;
          } else {
            int c2 = col - (DIN + CDIM);
            if (c2 < NH) ((float*)O2)[(size_t)row * NH + c2] = vv;
          }
        } else {
          size_t idx = (size_t)row * DM + col;
          float xn = vv + ((float*)O0)[idx];
          ((float*)O0)[idx] = xn;
          x16o[idx] = f2bf(xn);
          part[rg] += xn * xn;
        }
      }
    }
    if constexpr (MODE == 1) {
#pragma unroll
      for (int rg = 0; rg < 4; ++rg) {
#pragma unroll
        for (int off = 1; off < 16; off <<= 1) part[rg] += __shfl_xor(part[rg], off);
      }
      if ((lane & 15) == 0) {
#pragma unroll
        for (int rg = 0; rg < 4; ++rg)
          ssqo[(size_t)(m0 + rl0 + rg) * 24 + bx * 2 + (wn >> 5)] = part[rg];
      }
    }
  }
}

// ---------- conv(K=4)+silu; emits bf16 xs, dtx^T, B, C + fp32 dts (softplus'd) ----------
__global__ __launch_bounds__(256) void conv_dt_k(
    const float* __restrict__ xbc, const float* __restrict__ cw, const float* __restrict__ cb,
    const float* __restrict__ dtraw, const float* __restrict__ dbias,
    unsigned short* __restrict__ xs16, unsigned short* __restrict__ dtxT,
    unsigned short* __restrict__ Bbf, unsigned short* __restrict__ Cbf,
    float* __restrict__ dts) {
  __shared__ float stg[11][256];
  __shared__ float dtl[8][48];
  int tid = threadIdx.x;
  int chunk = blockIdx.x;                  // 0..6
  int bt0 = blockIdx.y * 8;
  int t0 = bt0 & (SEQ - 1);
  int cbase = chunk * 256;
  // vectorized float4 staging: 11 rows x 64 float4
  for (int f = tid; f < 11 * 64; f += 256) {
    int row = f >> 6, c4 = f & 63;
    int s = t0 - 3 + row;
    int col = cbase + c4 * 4;
    float4 v = {0.f, 0.f, 0.f, 0.f};
    if (s >= 0 && col + 3 < CDIM) {
      v = *(const float4*)(xbc + (size_t)(bt0 - 3 + row) * CDIM + col);
    }
    *(float4*)&stg[row][c4 * 4] = v;
  }
  if (chunk < 6) {
    for (int idx = tid; idx < 384; idx += 256) {
      int r = idx / 48, hh = idx - r * 48;
      dtl[r][hh] = sp(dtraw[(size_t)(bt0 + r) * NH + hh] + dbias[hh]);
    }
  }
  __syncthreads();
  int c = cbase + tid;
  if (chunk < 6) {
    float w0 = cw[c * 4], w1 = cw[c * 4 + 1], w2 = cw[c * 4 + 2], w3 = cw[c * 4 + 3];
    float bias = cb[c];
    int hh = c >> 5, p = c & 31, b = bt0 >> 9;
    s16x8 pk;
#pragma unroll
    for (int r = 0; r < 8; ++r) {
      float a = bias + stg[r][tid] * w0 + stg[r + 1][tid] * w1 + stg[r + 2][tid] * w2 +
                stg[r + 3][tid] * w3;
      float sv = a * sigm(a);
      xs16[(size_t)(bt0 + r) * DIN + c] = f2bf(sv);
      pk[r] = (short)f2bf(sv * dtl[r][hh]);
    }
    *reinterpret_cast<s16x8*>(dtxT + ((((size_t)b * NH + hh) * HP + p) * SEQ + t0)) = pk;
  } else if (tid < 128) {
    int cc = DIN + tid;
    float w0 = cw[cc * 4], w1 = cw[cc * 4 + 1], w2 = cw[cc * 4 + 2], w3 = cw[cc * 4 + 3];
    float bias = cb[cc];
#pragma unroll
    for (int r = 0; r < 8; ++r) {
      float a = bias + stg[r][tid] * w0 + stg[r + 1][tid] * w1 + stg[r + 2][tid] * w2 +
                stg[r + 3][tid] * w3;
      float sv = a * sigm(a);
      if (tid < 64) Bbf[(size_t)(bt0 + r) * NS + tid] = f2bf(sv);
      else          Cbf[(size_t)(bt0 + r) * NS + (tid - 64)] = f2bf(sv);
    }
  } else if (tid < 176) {
    int hh = tid - 128;
    float bias_ = dbias[hh];
    float v[8];
#pragma unroll
    for (int r = 0; r < 8; ++r) v[r] = sp(dtraw[(size_t)(bt0 + r) * NH + hh] + bias_);
    float4 a4 = {v[0], v[1], v[2], v[3]}, b4 = {v[4], v[5], v[6], v[7]};
    float* dp = dts + ((size_t)(bt0 >> 9) * NH + hh) * SEQ + t0;
    *(float4*)dp = a4;
    *(float4*)(dp + 4) = b4;
  }
}

// ---------- SSM: decay-truncated tiled semiseparable matmul + fused silu(z) gate ----------
__global__ __launch_bounds__(256) void scan_k(
    const unsigned short* __restrict__ Bbf, const unsigned short* __restrict__ Cbf,
    const unsigned short* __restrict__ dtxT, const unsigned short* __restrict__ xs16,
    const float* __restrict__ dts, const unsigned short* __restrict__ zb,
    const float* __restrict__ alog, const float* __restrict__ Dvec,
    unsigned short* __restrict__ g16, float* __restrict__ ssq2p) {
  __shared__ unsigned short CbPt[64 * 64];   // C tile, then reused as P tile
  __shared__ unsigned short Bb[2][64 * 64], Dx[2][32 * 64];
  __shared__ float lsb[SEQ];
  __shared__ float wtot[4];
  __shared__ int sfirst;
  int tid = threadIdx.x, lane = tid & 63, wv = tid >> 6;
  int tb = blockIdx.x, h = blockIdx.y, b = blockIdx.z;
  int t0 = tb * 64;
  const unsigned short* dxrow = dtxT + ((size_t)b * NH + h) * HP * SEQ;

  // issue C staging early
#pragma unroll
  for (int i = 0; i < 2; ++i) {
    int flt = i * 256 + tid, rr = flt >> 3, cc = flt & 7;
    gll16(Cbf + (size_t)(b * SEQ + t0 + rr) * NS + (cc ^ (rr & 7)) * 8, (char*)CbPt + flt * 16);
  }
  // ls = cumsum(dt*A) via shfl-scan (dt already softplus'd: dts)
  float Ah = -__expf(alog[h]);
  int t2 = tid * 2;
  float2 dv = *(const float2*)(dts + ((size_t)b * NH + h) * SEQ + t2);
  float d0 = dv.x * Ah, d1 = dv.y * Ah;
  float ps = d0 + d1;
  float v = ps;
#pragma unroll
  for (int off = 1; off < 64; off <<= 1) {
    float u = __shfl_up(v, off);
    if (lane >= off) v += u;
  }
  if (lane == 63) wtot[wv] = v;
  if (tid == 0) sfirst = tb;
  __syncthreads();
  float wpre = 0.f;
#pragma unroll
  for (int w = 0; w < 3; ++w) wpre += (w < wv) ? wtot[w] : 0.f;
  float excl = v + wpre - ps;
  lsb[t2] = excl + d0;
  lsb[t2 + 1] = excl + d0 + d1;
  __syncthreads();
  float REF = lsb[t0];
  // earliest s-tile with non-negligible decay (monotone predicate)
  if (tid < tb && (REF - lsb[tid * 64 + 63] >= -9.f)) atomicMin(&sfirst, tid);
  __syncthreads();
  int st0 = sfirst;

  // stage B/Dx for st0
#pragma unroll
  for (int i = 0; i < 2; ++i) {
    int flt = i * 256 + tid, rr = flt >> 3, cc = flt & 7;
    gll16(Bbf + (size_t)(b * SEQ + st0 * 64 + rr) * NS + (cc ^ (rr & 7)) * 8,
          (char*)Bb[st0 & 1] + flt * 16);
  }
  { int rr = tid >> 3, cc = tid & 7;
    gll16(dxrow + (size_t)rr * SEQ + st0 * 64 + (cc ^ (rr & 7)) * 8,
          (char*)Dx[st0 & 1] + tid * 16); }

  float lt[4], elt[4];
  int trb = wv * 16 + ((lane >> 4) << 2);
#pragma unroll
  for (int rg = 0; rg < 4; ++rg) {
    lt[rg] = lsb[t0 + trb + rg];
    elt[rg] = __expf(lt[rg] - REF);
  }
  s16x8 aC[2];
  f32x4 yacc[2] = {};

  for (int st = st0; st <= tb; ++st) {
    int s0 = st * 64;
    if (st < tb) {
      int s1 = s0 + 64;
#pragma unroll
      for (int i = 0; i < 2; ++i) {
        int flt = i * 256 + tid, rr = flt >> 3, cc = flt & 7;
        gll16(Bbf + (size_t)(b * SEQ + s1 + rr) * NS + (cc ^ (rr & 7)) * 8,
              (char*)Bb[(st + 1) & 1] + flt * 16);
      }
      { int rr = tid >> 3, cc = tid & 7;
        gll16(dxrow + (size_t)rr * SEQ + s1 + (cc ^ (rr & 7)) * 8,
              (char*)Dx[(st + 1) & 1] + tid * 16); }
      asm volatile("s_waitcnt vmcnt(3)" ::: "memory");
    } else {
      asm volatile("s_waitcnt vmcnt(0)" ::: "memory");
    }
    __builtin_amdgcn_s_barrier();
    __builtin_amdgcn_sched_barrier(0);
    const unsigned short* Bcur = Bb[st & 1];
    const unsigned short* Dcur = Dx[st & 1];
    if (st == st0) {   // C fragments (CbPt later reused as Pt; wave-local rows, safe)
#pragma unroll
      for (int ks = 0; ks < 2; ++ks) {
        int row = wv * 16 + (lane & 15);
        int ch = (ks * 4 + (lane >> 4)) ^ (row & 7);
        aC[ks] = *(const s16x8*)((const char*)CbPt + row * 128 + ch * 16);
      }
    }
    float lsv[4];
#pragma unroll
    for (int sq = 0; sq < 4; ++sq) lsv[sq] = lsb[s0 + sq * 16 + (lane & 15)];
    // G = C . B^T (wave's 16-row t-strip)
    f32x4 gf[4] = {};
    __builtin_amdgcn_s_setprio(1);
#pragma unroll
    for (int sq = 0; sq < 4; ++sq)
#pragma unroll
      for (int ks = 0; ks < 2; ++ks) {
        int row = sq * 16 + (lane & 15);
        int ch = (ks * 4 + (lane >> 4)) ^ (row & 7);
        s16x8 bB = *(const s16x8*)((const char*)Bcur + row * 128 + ch * 16);
        gf[sq] = mfma16(aC[ks], bB, gf[sq]);
      }
    __builtin_amdgcn_s_setprio(0);
    // decay weighting + write P (into CbPt)
    if (st < tb) {
      float es[4];
#pragma unroll
      for (int sq = 0; sq < 4; ++sq) es[sq] = __expf(REF - lsv[sq]);
#pragma unroll
      for (int sq = 0; sq < 4; ++sq) {
        int scol = sq * 16 + (lane & 15);
#pragma unroll
        for (int rg = 0; rg < 4; ++rg) {
          int trow = trb + rg;
          int off = (trow * 128 + scol * 2) ^ ((trow & 7) << 4);
          *(unsigned short*)((char*)CbPt + off) = f2bf(gf[sq][rg] * (elt[rg] * es[sq]));
        }
      }
    } else {
#pragma unroll
      for (int sq = 0; sq < 4; ++sq) {
        int scol = sq * 16 + (lane & 15);
        int sg = s0 + scol;
#pragma unroll
        for (int rg = 0; rg < 4; ++rg) {
          int trow = trb + rg, tg = t0 + trow;
          float wgt = (sg <= tg) ? __expf(lt[rg] - lsv[sq]) : 0.f;
          int off = (trow * 128 + scol * 2) ^ ((trow & 7) << 4);
          *(unsigned short*)((char*)CbPt + off) = f2bf(gf[sq][rg] * wgt);
        }
      }
    }
    // Y += P @ DxT (wave-local Pt rows)
    __builtin_amdgcn_s_setprio(1);
#pragma unroll
    for (int ks = 0; ks < 2; ++ks) {
      int row = wv * 16 + (lane & 15);
      int ch = (ks * 4 + (lane >> 4)) ^ (row & 7);
      s16x8 aP = *(const s16x8*)((const char*)CbPt + row * 128 + ch * 16);
#pragma unroll
      for (int pq = 0; pq < 2; ++pq) {
        int prow = pq * 16 + (lane & 15);
        int pch = (ks * 4 + (lane >> 4)) ^ (prow & 7);
        s16x8 bD = *(const s16x8*)((const char*)Dcur + prow * 128 + pch * 16);
        yacc[pq] = mfma16(aP, bD, yacc[pq]);
      }
    }
    __builtin_amdgcn_s_setprio(0);
    __builtin_amdgcn_s_barrier();
  }
  // epilogue: y = yacc + D*xs; g = y*silu(z); write g16 + ssq2p partial
  float Dh = Dvec[h];
  float part[4] = {0.f, 0.f, 0.f, 0.f};
#pragma unroll
  for (int pq = 0; pq < 2; ++pq) {
#pragma unroll
    for (int rg = 0; rg < 4; ++rg) {
      int trow = trb + rg;
      int tg = t0 + trow;
      int p = pq * 16 + (lane & 15);
      size_t gi = (size_t)(b * SEQ + tg) * DIN + h * HP + p;
      float xv = bf2f(xs16[gi]);
      float yv = yacc[pq][rg] + Dh * xv;
      float zf = bf2f(zb[gi]);
      float g = yv * zf * sigm(zf);
      g16[gi] = f2bf(g);
      part[rg] += g * g;
    }
  }
#pragma unroll
  for (int rg = 0; rg < 4; ++rg) {
#pragma unroll
    for (int off = 1; off < 16; off <<= 1) part[rg] += __shfl_xor(part[rg], off);
  }
  if ((lane & 15) == 0) {
#pragma unroll
    for (int rg = 0; rg < 4; ++rg)
      ssq2p[(size_t)(b * SEQ + t0 + trb + rg) * 48 + h] = part[rg];
  }
}

// ---------- tail: pool partials (fused final rmsnorm), proj (+chunk reduce), l2 ----------
__global__ void pool_part_k(const float* __restrict__ x, const float* __restrict__ ssq1p,
                            float* __restrict__ pp) {
  __shared__ float rsl[64];
  int b = blockIdx.y, tc = blockIdx.z, d0 = blockIdx.x * 256, tid = threadIdx.x;
  int t0 = tc * 64;
  if (tid < 64) {
    const float* p = ssq1p + (size_t)(b * SEQ + t0 + tid) * 24;
    float s = 0.f;
#pragma unroll
    for (int j = 0; j < 24; ++j) s += p[j];
    rsl[tid] = rsqrtf(s * (1.f / DM) + 1e-5f);
  }
  __syncthreads();
  int d = d0 + tid;
  float s = 0.f;
#pragma unroll 4
  for (int i = 0; i < 64; ++i) s += x[(size_t)(b * SEQ + t0 + i) * DM + d] * rsl[i];
  pp[((size_t)b * 8 + tc) * DM + d] = s;
}
__global__ void proj_k(const float* __restrict__ pp, const float* __restrict__ fnW,
                       const float* __restrict__ pW, const float* __restrict__ pb,
                       float* __restrict__ ptmp) {
  __shared__ float pl[DM];
  __shared__ float red[4][64];
  int e0 = blockIdx.x * 64, b = blockIdx.y, tid = threadIdx.x;
  for (int i = tid; i < DM; i += 256) {
    float s = 0.f;
#pragma unroll
    for (int c = 0; c < 8; ++c) s += pp[((size_t)b * 8 + c) * DM + i];
    pl[i] = s * (1.f / SEQ) * fnW[i];
  }
  __syncthreads();
  int el = tid & 63, g = tid >> 6;
  int e = e0 + el;
  float s = 0.f;
  for (int d = g * 192; d < (g + 1) * 192; ++d)
    s += pl[d] * pW[(size_t)d * EMBED + e];
  red[g][el] = s;
  __syncthreads();
  if (g == 0) ptmp[b * EMBED + e] = red[0][el] + red[1][el] + red[2][el] + red[3][el] + pb[e];
}
__global__ void l2_k(const float* __restrict__ ptmp, float* __restrict__ out) {
  int b = blockIdx.x;
  float v[6], ss = 0.f;
#pragma unroll
  for (int i = 0; i < 6; ++i) {
    v[i] = ptmp[(size_t)b * EMBED + threadIdx.x + i * 256];
    ss += v[i] * v[i];
  }
  float tot = block_sum<4>(ss);
  float inv = 1.f / fmaxf(sqrtf(tot), 1e-12f);
#pragma unroll
  for (int i = 0; i < 6; ++i)
    out[(size_t)b * EMBED + threadIdx.x + i * 256] = v[i] * inv;
}

// ---------- launch ----------
extern "C" void kernel_launch(void* const* d_in, const int* in_sizes, int n_in,
                              void* d_out, int out_size, void* d_ws, size_t ws_size,
                              hipStream_t stream) {
  const int*   tok  = (const int*)d_in[0];
  const float* embW = (const float*)d_in[1];
  const float* lnW  = (const float*)d_in[2];
  const float* ipW  = (const float*)d_in[3];
  const float* cW   = (const float*)d_in[4];
  const float* cB   = (const float*)d_in[5];
  const float* dtB  = (const float*)d_in[6];
  const float* Alog = (const float*)d_in[7];
  const float* Dv   = (const float*)d_in[8];
  const float* nW   = (const float*)d_in[9];
  const float* opW  = (const float*)d_in[10];
  const float* fnW  = (const float*)d_in[11];
  const float* pW   = (const float*)d_in[12];
  const float* pb   = (const float*)d_in[13];
  float* out = (float*)d_out;

  char* wsp = (char*)d_ws;
  auto alloc = [&](size_t bytes) {
    char* p = wsp;
    wsp += (bytes + 255) & ~(size_t)255;
    return p;
  };
  float* x      = (float*)alloc((size_t)ROWS * DM * 4);
  float* xbc    = (float*)alloc((size_t)ROWS * CDIM * 4);
  float* dtraw  = (float*)alloc((size_t)ROWS * NH * 4);
  float* dts    = (float*)alloc((size_t)BSZ * NH * SEQ * 4);
  float* ssq1p  = (float*)alloc((size_t)ROWS * 24 * 4);
  float* ssq2p  = (float*)alloc((size_t)ROWS * 48 * 4);
  float* pp     = (float*)alloc((size_t)BSZ * 8 * DM * 4);
  float* ptmp   = (float*)alloc((size_t)BSZ * EMBED * 4);
  unsigned short* x16   = (unsigned short*)alloc((size_t)ROWS * DM * 2);
  unsigned short* zb    = (unsigned short*)alloc((size_t)ROWS * DIN * 2);
  unsigned short* xs16  = (unsigned short*)alloc((size_t)ROWS * DIN * 2);
  unsigned short* g16   = (unsigned short*)alloc((size_t)ROWS * DIN * 2);
  unsigned short* dtxT  = (unsigned short*)alloc((size_t)BSZ * NH * HP * SEQ * 2);
  unsigned short* Bbf   = (unsigned short*)alloc((size_t)ROWS * NS * 2);
  unsigned short* Cbf   = (unsigned short*)alloc((size_t)ROWS * NS * 2);
  unsigned short* wtA   = (unsigned short*)alloc((size_t)NLAYERS * LDZX * DM * 2);
  unsigned short* wtO   = (unsigned short*)alloc((size_t)NLAYERS * DM * DIN * 2);

  embed_k<<<ROWS, 192, 0, stream>>>(tok, embW, x, x16, ssq1p);
  transpose_cvt<<<dim3(LDZX / 64, DM / 32, NLAYERS), 256, 0, stream>>>(
      ipW, lnW, wtA, DM, PROJ_IN, LDZX);
  transpose_cvt<<<dim3(DM / 64, DIN / 32, NLAYERS), 256, 0, stream>>>(
      opW, nW, wtO, DIN, DM, DM);

  for (int l = 0; l < NLAYERS; ++l) {
    gemm_k<128, 64, 0><<<dim3(LDZX / 64, ROWS / 128), 256, 0, stream>>>(
        x16, wtA + (size_t)l * LDZX * DM, DM, ssq1p, zb, xbc, dtraw, nullptr, nullptr);
    conv_dt_k<<<dim3(7, ROWS / 8), 256, 0, stream>>>(
        xbc, cW + (size_t)l * CDIM * 4, cB + (size_t)l * CDIM, dtraw, dtB + l * NH,
        xs16, dtxT, Bbf, Cbf, dts);
    scan_k<<<dim3(SEQ / 64, NH, BSZ), 256, 0, stream>>>(
        Bbf, Cbf, dtxT, xs16, dts, zb, Alog + l * NH, Dv + l * NH, g16, ssq2p);
    gemm_k<64, 64, 1><<<dim3(DM / 64, ROWS / 64), 256, 0, stream>>>(
        g16, wtO + (size_t)l * DM * DIN, DIN, ssq2p, x, nullptr, nullptr, x16, ssq1p);
  }

  pool_part_k<<<dim3(DM / 256, BSZ, 8), 256, 0, stream>>>(x, ssq1p, pp);
  proj_k<<<dim3(EMBED / 64, BSZ), 256, 0, stream>>>(pp, fnW, pW, pb, ptmp);
  l2_k<<<BSZ, 256, 0, stream>>>(ptmp, out);
}